// Round 6
// baseline (6401.154 us; speedup 1.0000x reference)
//
#include <hip/hip_runtime.h>

typedef unsigned int u32;
typedef unsigned short u16;
typedef unsigned long long u64;

#define ROWS 65536   // B*A
#define NB 1024
#define NA 64

__device__ __forceinline__ float dot4(float4 w, float4 x){
  return w.x*x.x + w.y*x.y + w.z*x.z + w.w*x.w;
}

// ---------------- actor_1 + attention: 8 rows per block, 128 threads ----------------
__global__ __launch_bounds__(128) void k_actor1(
    const float* __restrict__ obs, const float* __restrict__ w1, const float* __restrict__ b1,
    const float* __restrict__ lng, const float* __restrict__ lnb,
    const float* __restrict__ w2, const float* __restrict__ b2,
    const float* __restrict__ aw1, const float* __restrict__ ab1,
    const float* __restrict__ aw2, const float* __restrict__ ab2,
    const float* __restrict__ aw3, const float* __restrict__ ab3,
    float* __restrict__ thoughts, int* __restrict__ isinit)
{
  const int b0 = blockIdx.x * 8;
  const int t = threadIdx.x;
  __shared__ float4 xs[8][64];     // 8 obs rows (256 f32 each)
  __shared__ float hs[8][128];     // relu(LN(h))
  __shared__ float tb[8][128];     // thoughts
  __shared__ float ab[8][64];
  __shared__ float a2b[8][64];
  __shared__ float red[8][4];

  { const float4* og = (const float4*)(obs + (size_t)b0 * 256);
    #pragma unroll
    for (int j = 0; j < 4; j++){ int p = j * 128 + t; xs[p >> 6][p & 63] = og[p]; } }
  __syncthreads();

  // h = obs @ W1^T + b1   (thread t owns output feature t, streams W1 row t)
  float acc[8];
  #pragma unroll
  for (int r = 0; r < 8; r++) acc[r] = b1[t];
  { const float4* wr = (const float4*)(w1 + (size_t)t * 256);
    for (int j = 0; j < 64; j++){
      float4 w = wr[j];
      #pragma unroll
      for (int r = 0; r < 8; r++) acc[r] += dot4(w, xs[r][j]);
    } }

  // LayerNorm over 128 features (block = 2 waves)
  #pragma unroll
  for (int r = 0; r < 8; r++){
    float s = acc[r], s2 = acc[r] * acc[r];
    #pragma unroll
    for (int off = 32; off > 0; off >>= 1){ s += __shfl_down(s, off); s2 += __shfl_down(s2, off); }
    if ((t & 63) == 0){ red[r][t >> 6] = s; red[r][2 + (t >> 6)] = s2; }
  }
  __syncthreads();
  const float g_ = lng[t], bb_ = lnb[t];
  #pragma unroll
  for (int r = 0; r < 8; r++){
    float mu  = (red[r][0] + red[r][1]) * (1.0f/128.0f);
    float var = (red[r][2] + red[r][3]) * (1.0f/128.0f) - mu * mu;
    hs[r][t] = fmaxf((acc[r] - mu) * rsqrtf(var + 1e-5f) * g_ + bb_, 0.0f);
  }
  __syncthreads();

  // thoughts = relu(h) @ W2^T + b2
  float acc2[8];
  #pragma unroll
  for (int r = 0; r < 8; r++) acc2[r] = b2[t];
  { const float4* wr = (const float4*)(w2 + (size_t)t * 128);
    for (int j = 0; j < 32; j++){
      float4 w = wr[j];
      #pragma unroll
      for (int r = 0; r < 8; r++) acc2[r] += dot4(w, ((const float4*)hs[r])[j]);
    } }
  #pragma unroll
  for (int r = 0; r < 8; r++){
    thoughts[(size_t)(b0 + r) * 128 + t] = acc2[r];
    tb[r][t] = acc2[r];
  }
  __syncthreads();

  // attention MLP
  if (t < 64){
    float a[8];
    #pragma unroll
    for (int r = 0; r < 8; r++) a[r] = ab1[t];
    const float4* wr = (const float4*)(aw1 + (size_t)t * 128);
    for (int j = 0; j < 32; j++){
      float4 w = wr[j];
      #pragma unroll
      for (int r = 0; r < 8; r++) a[r] += dot4(w, ((const float4*)tb[r])[j]);
    }
    #pragma unroll
    for (int r = 0; r < 8; r++) ab[r][t] = fmaxf(a[r], 0.0f);
  }
  __syncthreads();
  if (t < 64){
    float a[8];
    #pragma unroll
    for (int r = 0; r < 8; r++) a[r] = ab2[t];
    const float4* wr = (const float4*)(aw2 + (size_t)t * 64);
    for (int j = 0; j < 16; j++){
      float4 w = wr[j];
      #pragma unroll
      for (int r = 0; r < 8; r++) a[r] += dot4(w, ((const float4*)ab[r])[j]);
    }
    #pragma unroll
    for (int r = 0; r < 8; r++) a2b[r][t] = fmaxf(a[r], 0.0f);
  }
  __syncthreads();
  if (t < 8){
    float p = ab3[0];
    for (int j = 0; j < 64; j++) p += aw3[j] * a2b[t][j];
    isinit[b0 + t] = (p > 0.0f) ? 1 : 0;   // sigmoid(p) > 0.5  <=>  p > 0
  }
}

// ---------------- K-nearest groups: one block per batch ----------------
__global__ __launch_bounds__(256) void k_groups(
    const float* __restrict__ thoughts, int* __restrict__ idxout)
{
  const int b = blockIdx.x;
  const int tid = threadIdx.x;
  __shared__ float T[64 * 130];
  __shared__ float sq[64];
  for (int p = tid; p < 8192; p += 256){
    T[(p >> 7) * 130 + (p & 127)] = thoughts[(size_t)b * 8192 + p];
  }
  __syncthreads();
  if (tid < 64){
    const float2* tj = (const float2*)&T[tid * 130];
    float s = 0.0f;
    #pragma unroll 8
    for (int k = 0; k < 64; k++){ float2 v = tj[k]; s += v.x*v.x + v.y*v.y; }
    sq[tid] = s;
  }
  __syncthreads();
  const int lane = tid & 63;
  const int wv = tid >> 6;
  const float2* tj = (const float2*)&T[lane * 130];
  const float sqj = sq[lane];
  for (int ii = 0; ii < 16; ii++){
    const int i = wv * 16 + ii;
    const float2* ti = (const float2*)&T[i * 130];
    float dot = 0.0f;
    #pragma unroll 8
    for (int k = 0; k < 64; k++){ float2 a = ti[k]; float2 c = tj[k]; dot += a.x*c.x + a.y*c.y; }
    float d = fmaxf(sq[i] + sqj - 2.0f*dot, 0.0f);   // clamp keeps uint-compare == float-compare
    u64 key = (((u64)__float_as_uint(d)) << 32) | (u32)lane;
    u64 mask = 0;
    for (int q = 0; q < 8; q++){
      u64 m = key;
      #pragma unroll
      for (int off = 32; off > 0; off >>= 1){ u64 o = __shfl_xor(m, off); if (o < m) m = o; }
      mask |= 1ull << (u32)(m & 63u);
      if (key == m) key = ~0ull;
    }
    if (lane == 0){
      u64 mm = mask;
      int base = (b * 64 + i) * 8;
      #pragma unroll
      for (int q = 0; q < 8; q++){ int j = (int)__builtin_ctzll(mm); mm &= mm - 1; idxout[base + q] = j; }
    }
  }
}

// ---------------- sequential gather -> bi-LSTM -> scatter: one block per batch ----------------
// 1024 threads: tid = dir(1b) | gate-row r(8b) | half hv(1b).
// Each thread holds HALF a wih row (64 f32) + HALF a whh row (32 f32) -> ~119 VGPR demand.
// Register-budget history: __launch_bounds__ 2nd arg maps to amdgpu-waves-per-eu MIN only;
// backend picked 8 waves/EU (2 blocks by LDS) => 64-VGPR cap => 17.7 GB spill traffic (r4/r5).
// amdgpu_waves_per_eu(4,4) pins min=max=4 waves/EU => 512/4 = 128-VGPR budget => zero spill.
__global__ __launch_bounds__(1024) __attribute__((amdgpu_waves_per_eu(4, 4)))
void k_scan(
    const float* __restrict__ thoughts, const int* __restrict__ isinit, const int* __restrict__ idx,
    const float* __restrict__ wihf, const float* __restrict__ whhf,
    const float* __restrict__ bihf, const float* __restrict__ bhhf,
    const float* __restrict__ wihb, const float* __restrict__ whhb,
    const float* __restrict__ bihb, const float* __restrict__ bhhb,
    float* __restrict__ newt)
{
  const int b = blockIdx.x;
  const int tid = threadIdx.x;
  const int dir = tid >> 9;          // 0 fwd, 1 bwd
  const int r   = (tid >> 1) & 255;  // gate row
  const int hv  = tid & 1;           // which half of the K dimension

  __shared__ float nt[64 * 128];
  __shared__ __align__(16) float4 X4s[8 * 32];
  __shared__ float zb[2][256];
  __shared__ __align__(16) float hbv[2][64];
  __shared__ int gall[512];
  __shared__ int flags[64];
  float* X = (float*)X4s;

  const float* wih = dir ? wihb : wihf;
  const float* whh = dir ? whhb : whhf;
  float4 wihr[16];   // wih[r, hv*64 .. hv*64+64)
  { const float4* wp = (const float4*)(wih + (size_t)r * 128 + hv * 64);
    #pragma unroll
    for (int j = 0; j < 16; j++) wihr[j] = wp[j]; }
  float4 whhr[8];    // whh[r, hv*32 .. hv*32+32)
  { const float4* wp = (const float4*)(whh + (size_t)r * 64 + hv * 32);
    #pragma unroll
    for (int j = 0; j < 8; j++) whhr[j] = wp[j]; }
  const float bias = dir ? (bihb[r] + bhhb[r]) : (bihf[r] + bhhf[r]);

  for (int p = tid; p < 8192; p += 1024) nt[p] = thoughts[(size_t)b * 8192 + p];
  if (tid < 512) gall[tid] = idx[(size_t)b * 512 + tid];
  if (tid < 64) flags[tid] = isinit[b * 64 + tid];
  __syncthreads();

  float c = 0.0f;   // cell state, meaningful on gate threads (hv==0 && r<64)
  #pragma unroll 1
  for (int i = 0; i < 64; i++){
    if (!flags[i]) continue;            // uniform across block
    const int* gi = &gall[i * 8];
    X[tid] = nt[gi[tid >> 7] * 128 + (tid & 127)];   // gather 8 rows, 1 elem/thread
    __syncthreads();

    // Zx[t] partial = wih_half . X[t]_half  for all 8 timesteps; combine with partner
    float acc[8];
    #pragma unroll
    for (int t = 0; t < 8; t++) acc[t] = hv ? 0.0f : bias;
    #pragma unroll
    for (int j = 0; j < 16; j++){
      float4 w = wihr[j];
      #pragma unroll
      for (int t = 0; t < 8; t++) acc[t] += dot4(w, X4s[t * 32 + hv * 16 + j]);
    }
    #pragma unroll
    for (int t = 0; t < 8; t++) acc[t] += __shfl_xor(acc[t], 1);   // both halves hold full Zx

    // recurrence: 8 steps, fwd consumes Zx[s], bwd consumes Zx[7-s]
    c = 0.0f;
    #pragma unroll 1
    for (int s = 0; s < 8; s++){
      float z = 0.0f;
      if (s > 0){
        const float4* h4 = (const float4*)&hbv[dir][hv * 32];
        #pragma unroll
        for (int j = 0; j < 8; j++) z += dot4(whhr[j], h4[j]);
      }
      z += __shfl_xor(z, 1);
      if (!hv) zb[dir][r] = (dir ? acc[7 - s] : acc[s]) + z;
      __syncthreads();
      if (!hv && r < 64){
        const int tt = dir ? (7 - s) : s;
        float zi = zb[dir][r], zf = zb[dir][64+r], zg = zb[dir][128+r], zo = zb[dir][192+r];
        float fi = 1.0f/(1.0f + expf(-zi));
        float ff = 1.0f/(1.0f + expf(-zf));
        float fg = tanhf(zg);
        float fo = 1.0f/(1.0f + expf(-zo));
        c = ff*c + fi*fg;
        float hn = fo * tanhf(c);
        hbv[dir][r] = hn;
        nt[gi[tt] * 128 + dir * 64 + r] = hn;
      }
      __syncthreads();
    }
  }
  for (int p = tid; p < 8192; p += 1024) newt[(size_t)b * 8192 + p] = nt[p];
}

// ---------------- actor_2: 8 rows per block, 128 threads ----------------
__global__ __launch_bounds__(128) void k_actor2(
    const float* __restrict__ thoughts, const float* __restrict__ newt,
    const float* __restrict__ w1, const float* __restrict__ b1, const float* __restrict__ w2,
    float* __restrict__ out)
{
  const int b0 = blockIdx.x * 8;
  const int t = threadIdx.x;
  __shared__ float xs[8][256];
  __shared__ float ybuf[8][128];
  for (int p = t; p < 2048; p += 128){
    int r = p >> 8, c = p & 255;
    float v = (c < 128) ? thoughts[(size_t)(b0 + r) * 128 + c]
                        : newt[(size_t)(b0 + r) * 128 + (c - 128)];
    xs[r][c] = fmaxf(v, 0.0f);
  }
  __syncthreads();
  float acc[8];
  #pragma unroll
  for (int r = 0; r < 8; r++) acc[r] = b1[t];
  { const float4* wr = (const float4*)(w1 + (size_t)t * 256);
    for (int j = 0; j < 64; j++){
      float4 w = wr[j];
      #pragma unroll
      for (int r = 0; r < 8; r++) acc[r] += dot4(w, ((const float4*)xs[r])[j]);
    } }
  #pragma unroll
  for (int r = 0; r < 8; r++) ybuf[r][t] = acc[r];
  __syncthreads();
  if (t < 64){
    float a[8];
    #pragma unroll
    for (int r = 0; r < 8; r++) a[r] = 0.0f;
    const float4* wr = (const float4*)(w2 + (size_t)t * 128);
    for (int j = 0; j < 32; j++){
      float4 w = wr[j];
      #pragma unroll
      for (int r = 0; r < 8; r++) a[r] += dot4(w, ((const float4*)ybuf[r])[j]);
    }
    #pragma unroll
    for (int r = 0; r < 8; r++) out[(size_t)(b0 + r) * 64 + t] = tanhf(a[r]);
  }
}

extern "C" void kernel_launch(void* const* d_in, const int* in_sizes, int n_in,
                              void* d_out, int out_size, void* d_ws, size_t ws_size,
                              hipStream_t stream)
{
  const float* obs  = (const float*)d_in[0];
  const float* w1   = (const float*)d_in[1];
  const float* b1   = (const float*)d_in[2];
  const float* lng  = (const float*)d_in[3];
  const float* lnb  = (const float*)d_in[4];
  const float* w2   = (const float*)d_in[5];
  const float* b2   = (const float*)d_in[6];
  const float* aw1  = (const float*)d_in[7];
  const float* ab1  = (const float*)d_in[8];
  const float* aw2  = (const float*)d_in[9];
  const float* ab2  = (const float*)d_in[10];
  const float* aw3  = (const float*)d_in[11];
  const float* ab3  = (const float*)d_in[12];
  const float* wihf = (const float*)d_in[13];
  const float* whhf = (const float*)d_in[14];
  const float* bihf = (const float*)d_in[15];
  const float* bhhf = (const float*)d_in[16];
  const float* wihb = (const float*)d_in[17];
  const float* whhb = (const float*)d_in[18];
  const float* bihb = (const float*)d_in[19];
  const float* bhhb = (const float*)d_in[20];
  const float* a2w1 = (const float*)d_in[21];
  const float* a2b1 = (const float*)d_in[22];
  const float* a2w2 = (const float*)d_in[23];

  float* thoughts = (float*)d_ws;                       // 33.5 MB
  float* newt     = thoughts + (size_t)ROWS * 128;      // 33.5 MB
  int*   isinit   = (int*)(newt + (size_t)ROWS * 128);  // 256 KB
  int*   idxb     = isinit + ROWS;                      // 2 MB

  hipLaunchKernelGGL(k_actor1, dim3(ROWS / 8), dim3(128), 0, stream,
                     obs, w1, b1, lng, lnb, w2, b2, aw1, ab1, aw2, ab2, aw3, ab3,
                     thoughts, isinit);
  hipLaunchKernelGGL(k_groups, dim3(NB), dim3(256), 0, stream, thoughts, idxb);
  hipLaunchKernelGGL(k_scan, dim3(NB), dim3(1024), 0, stream,
                     thoughts, isinit, idxb,
                     wihf, whhf, bihf, bhhf, wihb, whhb, bihb, bhhb, newt);
  hipLaunchKernelGGL(k_actor2, dim3(ROWS / 8), dim3(128), 0, stream,
                     thoughts, newt, a2w1, a2b1, a2w2, (float*)d_out);
}

// Round 8
// 1703.379 us; speedup vs baseline: 3.7579x; 3.7579x over previous
//
#include <hip/hip_runtime.h>

typedef unsigned int u32;
typedef unsigned short u16;
typedef unsigned long long u64;
typedef _Float16 h2 __attribute__((ext_vector_type(2)));

#define ROWS 65536   // B*A
#define NB 1024
#define NA 64

__device__ __forceinline__ float dot4(float4 w, float4 x){
  return w.x*x.x + w.y*x.y + w.z*x.z + w.w*x.w;
}
__device__ __forceinline__ h2 u32_h2(u32 v){ union { u32 u; h2 h; } x; x.u = v; return x.h; }
__device__ __forceinline__ h2 pack_h2(float a, float b){ h2 r; r.x = (_Float16)a; r.y = (_Float16)b; return r; }

// ---------------- actor_1 + attention: 8 rows per block, 128 threads ----------------
__global__ __launch_bounds__(128) void k_actor1(
    const float* __restrict__ obs, const float* __restrict__ w1, const float* __restrict__ b1,
    const float* __restrict__ lng, const float* __restrict__ lnb,
    const float* __restrict__ w2, const float* __restrict__ b2,
    const float* __restrict__ aw1, const float* __restrict__ ab1,
    const float* __restrict__ aw2, const float* __restrict__ ab2,
    const float* __restrict__ aw3, const float* __restrict__ ab3,
    float* __restrict__ thoughts, int* __restrict__ isinit)
{
  const int b0 = blockIdx.x * 8;
  const int t = threadIdx.x;
  __shared__ float4 xs[8][64];     // 8 obs rows (256 f32 each)
  __shared__ float hs[8][128];     // relu(LN(h))
  __shared__ float tb[8][128];     // thoughts
  __shared__ float ab[8][64];
  __shared__ float a2b[8][64];
  __shared__ float red[8][4];

  { const float4* og = (const float4*)(obs + (size_t)b0 * 256);
    #pragma unroll
    for (int j = 0; j < 4; j++){ int p = j * 128 + t; xs[p >> 6][p & 63] = og[p]; } }
  __syncthreads();

  // h = obs @ W1^T + b1   (thread t owns output feature t, streams W1 row t)
  float acc[8];
  #pragma unroll
  for (int r = 0; r < 8; r++) acc[r] = b1[t];
  { const float4* wr = (const float4*)(w1 + (size_t)t * 256);
    for (int j = 0; j < 64; j++){
      float4 w = wr[j];
      #pragma unroll
      for (int r = 0; r < 8; r++) acc[r] += dot4(w, xs[r][j]);
    } }

  // LayerNorm over 128 features (block = 2 waves)
  #pragma unroll
  for (int r = 0; r < 8; r++){
    float s = acc[r], s2 = acc[r] * acc[r];
    #pragma unroll
    for (int off = 32; off > 0; off >>= 1){ s += __shfl_down(s, off); s2 += __shfl_down(s2, off); }
    if ((t & 63) == 0){ red[r][t >> 6] = s; red[r][2 + (t >> 6)] = s2; }
  }
  __syncthreads();
  const float g_ = lng[t], bb_ = lnb[t];
  #pragma unroll
  for (int r = 0; r < 8; r++){
    float mu  = (red[r][0] + red[r][1]) * (1.0f/128.0f);
    float var = (red[r][2] + red[r][3]) * (1.0f/128.0f) - mu * mu;
    hs[r][t] = fmaxf((acc[r] - mu) * rsqrtf(var + 1e-5f) * g_ + bb_, 0.0f);
  }
  __syncthreads();

  // thoughts = relu(h) @ W2^T + b2
  float acc2[8];
  #pragma unroll
  for (int r = 0; r < 8; r++) acc2[r] = b2[t];
  { const float4* wr = (const float4*)(w2 + (size_t)t * 128);
    for (int j = 0; j < 32; j++){
      float4 w = wr[j];
      #pragma unroll
      for (int r = 0; r < 8; r++) acc2[r] += dot4(w, ((const float4*)hs[r])[j]);
    } }
  #pragma unroll
  for (int r = 0; r < 8; r++){
    thoughts[(size_t)(b0 + r) * 128 + t] = acc2[r];
    tb[r][t] = acc2[r];
  }
  __syncthreads();

  // attention MLP
  if (t < 64){
    float a[8];
    #pragma unroll
    for (int r = 0; r < 8; r++) a[r] = ab1[t];
    const float4* wr = (const float4*)(aw1 + (size_t)t * 128);
    for (int j = 0; j < 32; j++){
      float4 w = wr[j];
      #pragma unroll
      for (int r = 0; r < 8; r++) a[r] += dot4(w, ((const float4*)tb[r])[j]);
    }
    #pragma unroll
    for (int r = 0; r < 8; r++) ab[r][t] = fmaxf(a[r], 0.0f);
  }
  __syncthreads();
  if (t < 64){
    float a[8];
    #pragma unroll
    for (int r = 0; r < 8; r++) a[r] = ab2[t];
    const float4* wr = (const float4*)(aw2 + (size_t)t * 64);
    for (int j = 0; j < 16; j++){
      float4 w = wr[j];
      #pragma unroll
      for (int r = 0; r < 8; r++) a[r] += dot4(w, ((const float4*)ab[r])[j]);
    }
    #pragma unroll
    for (int r = 0; r < 8; r++) a2b[r][t] = fmaxf(a[r], 0.0f);
  }
  __syncthreads();
  if (t < 8){
    float p = ab3[0];
    for (int j = 0; j < 64; j++) p += aw3[j] * a2b[t][j];
    isinit[b0 + t] = (p > 0.0f) ? 1 : 0;   // sigmoid(p) > 0.5  <=>  p > 0
  }
}

// ---------------- K-nearest groups: one block per batch ----------------
__global__ __launch_bounds__(256) void k_groups(
    const float* __restrict__ thoughts, int* __restrict__ idxout)
{
  const int b = blockIdx.x;
  const int tid = threadIdx.x;
  __shared__ float T[64 * 130];
  __shared__ float sq[64];
  for (int p = tid; p < 8192; p += 256){
    T[(p >> 7) * 130 + (p & 127)] = thoughts[(size_t)b * 8192 + p];
  }
  __syncthreads();
  if (tid < 64){
    const float2* tj = (const float2*)&T[tid * 130];
    float s = 0.0f;
    #pragma unroll 8
    for (int k = 0; k < 64; k++){ float2 v = tj[k]; s += v.x*v.x + v.y*v.y; }
    sq[tid] = s;
  }
  __syncthreads();
  const int lane = tid & 63;
  const int wv = tid >> 6;
  const float2* tj = (const float2*)&T[lane * 130];
  const float sqj = sq[lane];
  for (int ii = 0; ii < 16; ii++){
    const int i = wv * 16 + ii;
    const float2* ti = (const float2*)&T[i * 130];
    float dot = 0.0f;
    #pragma unroll 8
    for (int k = 0; k < 64; k++){ float2 a = ti[k]; float2 c = tj[k]; dot += a.x*c.x + a.y*c.y; }
    float d = fmaxf(sq[i] + sqj - 2.0f*dot, 0.0f);   // clamp keeps uint-compare == float-compare
    u64 key = (((u64)__float_as_uint(d)) << 32) | (u32)lane;
    u64 mask = 0;
    for (int q = 0; q < 8; q++){
      u64 m = key;
      #pragma unroll
      for (int off = 32; off > 0; off >>= 1){ u64 o = __shfl_xor(m, off); if (o < m) m = o; }
      mask |= 1ull << (u32)(m & 63u);
      if (key == m) key = ~0ull;
    }
    if (lane == 0){
      u64 mm = mask;
      int base = (b * 64 + i) * 8;
      #pragma unroll
      for (int q = 0; q < 8; q++){ int j = (int)__builtin_ctzll(mm); mm &= mm - 1; idxout[base + q] = j; }
    }
  }
}

// ---------------- sequential gather -> bi-LSTM -> scatter: one block per batch ----------------
// 512 threads: dir = tid>>8, gate row r = tid&255.
// VGPR-budget facts (measured r2 vs r4/r5/r6): 512-thr block + ~40 KB LDS => 128-VGPR budget;
// 1024-thr => 64; launch_bounds arg2 / amdgpu_waves_per_eu do NOT raise it.
// So: fit 128 structurally. Weights live as PACKED half2 feeding v_dot2_f32_f16
// (__builtin_amdgcn_fdot2) -- the packed reg is the HW operand, so there is no f32
// expansion for LLVM to hoist (r3's failure mode). Demand: wih 64 h2 + whh 32 h2
// + acc[8] f32 + temps ~= 120 < 128 => zero scratch.
__global__ __launch_bounds__(512) void k_scan(
    const float* __restrict__ thoughts, const int* __restrict__ isinit, const int* __restrict__ idx,
    const float* __restrict__ wihf, const float* __restrict__ whhf,
    const float* __restrict__ bihf, const float* __restrict__ bhhf,
    const float* __restrict__ wihb, const float* __restrict__ whhb,
    const float* __restrict__ bihb, const float* __restrict__ bhhb,
    float* __restrict__ newt)
{
  const int b = blockIdx.x;
  const int tid = threadIdx.x;
  const int dir = tid >> 8;          // 0 fwd, 1 bwd
  const int r   = tid & 255;         // gate row

  __shared__ float nt[64 * 128];                       // 32 KB state
  __shared__ __align__(16) _Float16 X16[8 * 128];      // gathered X snapshot, f16 (2 KB)
  __shared__ float zb[2][256];
  __shared__ __align__(16) _Float16 hb16[2][64];       // h state, f16 for the dot
  __shared__ int gall[512];
  __shared__ int flags[64];

  const float* wih = dir ? wihb : wihf;
  const float* whh = dir ? whhb : whhf;
  h2 wih2[64];   // full row, packed f16 pairs
  { const float2* wp = (const float2*)(wih + (size_t)r * 128);
    #pragma unroll
    for (int j = 0; j < 64; j++){ float2 w = wp[j]; wih2[j] = pack_h2(w.x, w.y); } }
  h2 whh2[32];
  { const float2* wp = (const float2*)(whh + (size_t)r * 64);
    #pragma unroll
    for (int j = 0; j < 32; j++){ float2 w = wp[j]; whh2[j] = pack_h2(w.x, w.y); } }
  const float bias = dir ? (bihb[r] + bhhb[r]) : (bihf[r] + bhhf[r]);

  for (int p = tid; p < 8192; p += 512) nt[p] = thoughts[(size_t)b * 8192 + p];
  gall[tid] = idx[(size_t)b * 512 + tid];
  if (tid < 64) flags[tid] = isinit[b * 64 + tid];
  __syncthreads();

  #pragma unroll 1
  for (int i = 0; i < 64; i++){
    if (!flags[i]) continue;            // uniform across block
    const int* gi = &gall[i * 8];
    { const int t = tid >> 6, cc = tid & 63;      // snapshot X -> f16 (1 half2/thread)
      float a  = nt[gi[t] * 128 + 2 * cc];
      float bv = nt[gi[t] * 128 + 2 * cc + 1];
      ((h2*)X16)[tid] = pack_h2(a, bv); }
    __syncthreads();

    // Zx[t] = bias + Wih[r,:] . X[t,:]  (full row per thread, v_dot2_f32_f16)
    float acc[8];
    #pragma unroll
    for (int t = 0; t < 8; t++) acc[t] = bias;
    #pragma unroll
    for (int t = 0; t < 8; t++){
      const uint4* Xr = (const uint4*)&X16[t * 128];
      #pragma unroll
      for (int j4 = 0; j4 < 16; j4++){
        uint4 q = Xr[j4];
        acc[t] = __builtin_amdgcn_fdot2(wih2[4*j4+0], u32_h2(q.x), acc[t], false);
        acc[t] = __builtin_amdgcn_fdot2(wih2[4*j4+1], u32_h2(q.y), acc[t], false);
        acc[t] = __builtin_amdgcn_fdot2(wih2[4*j4+2], u32_h2(q.z), acc[t], false);
        acc[t] = __builtin_amdgcn_fdot2(wih2[4*j4+3], u32_h2(q.w), acc[t], false);
      }
    }

    // recurrence: 8 steps, fwd consumes Zx[s], bwd consumes Zx[7-s]
    float c = 0.0f;
    #pragma unroll 1
    for (int s = 0; s < 8; s++){
      float z = dir ? acc[7 - s] : acc[s];
      if (s > 0){
        const uint4* hq = (const uint4*)&hb16[dir][0];   // broadcast reads
        #pragma unroll
        for (int j4 = 0; j4 < 8; j4++){
          uint4 q = hq[j4];
          z = __builtin_amdgcn_fdot2(whh2[4*j4+0], u32_h2(q.x), z, false);
          z = __builtin_amdgcn_fdot2(whh2[4*j4+1], u32_h2(q.y), z, false);
          z = __builtin_amdgcn_fdot2(whh2[4*j4+2], u32_h2(q.z), z, false);
          z = __builtin_amdgcn_fdot2(whh2[4*j4+3], u32_h2(q.w), z, false);
        }
      }
      zb[dir][r] = z;
      __syncthreads();
      if (r < 64){
        const int tt = dir ? (7 - s) : s;
        float zi = zb[dir][r], zf = zb[dir][64+r], zg = zb[dir][128+r], zo = zb[dir][192+r];
        float fi = 1.0f/(1.0f + expf(-zi));
        float ff = 1.0f/(1.0f + expf(-zf));
        float fg = tanhf(zg);
        float fo = 1.0f/(1.0f + expf(-zo));
        c = ff*c + fi*fg;
        float hn = fo * tanhf(c);
        hb16[dir][r] = (_Float16)hn;             // f16 copy for the Whh dot
        nt[gi[tt] * 128 + dir * 64 + r] = hn;    // full-precision state update
      }
      __syncthreads();
    }
  }
  for (int p = tid; p < 8192; p += 512) newt[(size_t)b * 8192 + p] = nt[p];
}

// ---------------- actor_2: 8 rows per block, 128 threads ----------------
__global__ __launch_bounds__(128) void k_actor2(
    const float* __restrict__ thoughts, const float* __restrict__ newt,
    const float* __restrict__ w1, const float* __restrict__ b1, const float* __restrict__ w2,
    float* __restrict__ out)
{
  const int b0 = blockIdx.x * 8;
  const int t = threadIdx.x;
  __shared__ float xs[8][256];
  __shared__ float ybuf[8][128];
  for (int p = t; p < 2048; p += 128){
    int r = p >> 8, c = p & 255;
    float v = (c < 128) ? thoughts[(size_t)(b0 + r) * 128 + c]
                        : newt[(size_t)(b0 + r) * 128 + (c - 128)];
    xs[r][c] = fmaxf(v, 0.0f);
  }
  __syncthreads();
  float acc[8];
  #pragma unroll
  for (int r = 0; r < 8; r++) acc[r] = b1[t];
  { const float4* wr = (const float4*)(w1 + (size_t)t * 256);
    for (int j = 0; j < 64; j++){
      float4 w = wr[j];
      #pragma unroll
      for (int r = 0; r < 8; r++) acc[r] += dot4(w, ((const float4*)xs[r])[j]);
    } }
  #pragma unroll
  for (int r = 0; r < 8; r++) ybuf[r][t] = acc[r];
  __syncthreads();
  if (t < 64){
    float a[8];
    #pragma unroll
    for (int r = 0; r < 8; r++) a[r] = 0.0f;
    const float4* wr = (const float4*)(w2 + (size_t)t * 128);
    for (int j = 0; j < 32; j++){
      float4 w = wr[j];
      #pragma unroll
      for (int r = 0; r < 8; r++) a[r] += dot4(w, ((const float4*)ybuf[r])[j]);
    }
    #pragma unroll
    for (int r = 0; r < 8; r++) out[(size_t)(b0 + r) * 64 + t] = tanhf(a[r]);
  }
}

extern "C" void kernel_launch(void* const* d_in, const int* in_sizes, int n_in,
                              void* d_out, int out_size, void* d_ws, size_t ws_size,
                              hipStream_t stream)
{
  const float* obs  = (const float*)d_in[0];
  const float* w1   = (const float*)d_in[1];
  const float* b1   = (const float*)d_in[2];
  const float* lng  = (const float*)d_in[3];
  const float* lnb  = (const float*)d_in[4];
  const float* w2   = (const float*)d_in[5];
  const float* b2   = (const float*)d_in[6];
  const float* aw1  = (const float*)d_in[7];
  const float* ab1  = (const float*)d_in[8];
  const float* aw2  = (const float*)d_in[9];
  const float* ab2  = (const float*)d_in[10];
  const float* aw3  = (const float*)d_in[11];
  const float* ab3  = (const float*)d_in[12];
  const float* wihf = (const float*)d_in[13];
  const float* whhf = (const float*)d_in[14];
  const float* bihf = (const float*)d_in[15];
  const float* bhhf = (const float*)d_in[16];
  const float* wihb = (const float*)d_in[17];
  const float* whhb = (const float*)d_in[18];
  const float* bihb = (const float*)d_in[19];
  const float* bhhb = (const float*)d_in[20];
  const float* a2w1 = (const float*)d_in[21];
  const float* a2b1 = (const float*)d_in[22];
  const float* a2w2 = (const float*)d_in[23];

  float* thoughts = (float*)d_ws;                       // 33.5 MB
  float* newt     = thoughts + (size_t)ROWS * 128;      // 33.5 MB
  int*   isinit   = (int*)(newt + (size_t)ROWS * 128);  // 256 KB
  int*   idxb     = isinit + ROWS;                      // 2 MB

  hipLaunchKernelGGL(k_actor1, dim3(ROWS / 8), dim3(128), 0, stream,
                     obs, w1, b1, lng, lnb, w2, b2, aw1, ab1, aw2, ab2, aw3, ab3,
                     thoughts, isinit);
  hipLaunchKernelGGL(k_groups, dim3(NB), dim3(256), 0, stream, thoughts, idxb);
  hipLaunchKernelGGL(k_scan, dim3(NB), dim3(512), 0, stream,
                     thoughts, isinit, idxb,
                     wihf, whhf, bihf, bhhf, wihb, whhb, bihb, bhhb, newt);
  hipLaunchKernelGGL(k_actor2, dim3(ROWS / 8), dim3(128), 0, stream,
                     thoughts, newt, a2w1, a2b1, a2w2, (float*)d_out);
}

// Round 9
// 1415.141 us; speedup vs baseline: 4.5233x; 1.2037x over previous
//
#include <hip/hip_runtime.h>

typedef unsigned int u32;
typedef unsigned short u16;
typedef unsigned long long u64;
typedef _Float16 h2 __attribute__((ext_vector_type(2)));

#define ROWS 65536   // B*A
#define NB 1024
#define NA 64

__device__ __forceinline__ float dot4(float4 w, float4 x){
  return w.x*x.x + w.y*x.y + w.z*x.z + w.w*x.w;
}
__device__ __forceinline__ h2 u32_h2(u32 v){ union { u32 u; h2 h; } x; x.u = v; return x.h; }
__device__ __forceinline__ h2 pack_h2(float a, float b){ h2 r; r.x = (_Float16)a; r.y = (_Float16)b; return r; }
// fast sigmoid/tanh on v_exp_f32 + v_rcp_f32 (~1 ulp each; threshold is 1.1e-2)
__device__ __forceinline__ float fsig(float z){
  float e = __builtin_amdgcn_exp2f(-1.44269504f * z);
  return __builtin_amdgcn_rcpf(1.0f + e);
}
__device__ __forceinline__ float ftanh(float z){
  float e = __builtin_amdgcn_exp2f(2.885390082f * z);
  return 1.0f - 2.0f * __builtin_amdgcn_rcpf(1.0f + e);
}

// ---------------- actor_1 + attention: 8 rows per block, 128 threads ----------------
__global__ __launch_bounds__(128) void k_actor1(
    const float* __restrict__ obs, const float* __restrict__ w1, const float* __restrict__ b1,
    const float* __restrict__ lng, const float* __restrict__ lnb,
    const float* __restrict__ w2, const float* __restrict__ b2,
    const float* __restrict__ aw1, const float* __restrict__ ab1,
    const float* __restrict__ aw2, const float* __restrict__ ab2,
    const float* __restrict__ aw3, const float* __restrict__ ab3,
    float* __restrict__ thoughts, int* __restrict__ isinit)
{
  const int b0 = blockIdx.x * 8;
  const int t = threadIdx.x;
  __shared__ float4 xs[8][64];     // 8 obs rows (256 f32 each)
  __shared__ float hs[8][128];     // relu(LN(h))
  __shared__ float tb[8][128];     // thoughts
  __shared__ float ab[8][64];
  __shared__ float a2b[8][64];
  __shared__ float red[8][4];

  { const float4* og = (const float4*)(obs + (size_t)b0 * 256);
    #pragma unroll
    for (int j = 0; j < 4; j++){ int p = j * 128 + t; xs[p >> 6][p & 63] = og[p]; } }
  __syncthreads();

  // h = obs @ W1^T + b1   (thread t owns output feature t, streams W1 row t)
  float acc[8];
  #pragma unroll
  for (int r = 0; r < 8; r++) acc[r] = b1[t];
  { const float4* wr = (const float4*)(w1 + (size_t)t * 256);
    for (int j = 0; j < 64; j++){
      float4 w = wr[j];
      #pragma unroll
      for (int r = 0; r < 8; r++) acc[r] += dot4(w, xs[r][j]);
    } }

  // LayerNorm over 128 features (block = 2 waves)
  #pragma unroll
  for (int r = 0; r < 8; r++){
    float s = acc[r], s2 = acc[r] * acc[r];
    #pragma unroll
    for (int off = 32; off > 0; off >>= 1){ s += __shfl_down(s, off); s2 += __shfl_down(s2, off); }
    if ((t & 63) == 0){ red[r][t >> 6] = s; red[r][2 + (t >> 6)] = s2; }
  }
  __syncthreads();
  const float g_ = lng[t], bb_ = lnb[t];
  #pragma unroll
  for (int r = 0; r < 8; r++){
    float mu  = (red[r][0] + red[r][1]) * (1.0f/128.0f);
    float var = (red[r][2] + red[r][3]) * (1.0f/128.0f) - mu * mu;
    hs[r][t] = fmaxf((acc[r] - mu) * rsqrtf(var + 1e-5f) * g_ + bb_, 0.0f);
  }
  __syncthreads();

  // thoughts = relu(h) @ W2^T + b2
  float acc2[8];
  #pragma unroll
  for (int r = 0; r < 8; r++) acc2[r] = b2[t];
  { const float4* wr = (const float4*)(w2 + (size_t)t * 128);
    for (int j = 0; j < 32; j++){
      float4 w = wr[j];
      #pragma unroll
      for (int r = 0; r < 8; r++) acc2[r] += dot4(w, ((const float4*)hs[r])[j]);
    } }
  #pragma unroll
  for (int r = 0; r < 8; r++){
    thoughts[(size_t)(b0 + r) * 128 + t] = acc2[r];
    tb[r][t] = acc2[r];
  }
  __syncthreads();

  // attention MLP
  if (t < 64){
    float a[8];
    #pragma unroll
    for (int r = 0; r < 8; r++) a[r] = ab1[t];
    const float4* wr = (const float4*)(aw1 + (size_t)t * 128);
    for (int j = 0; j < 32; j++){
      float4 w = wr[j];
      #pragma unroll
      for (int r = 0; r < 8; r++) a[r] += dot4(w, ((const float4*)tb[r])[j]);
    }
    #pragma unroll
    for (int r = 0; r < 8; r++) ab[r][t] = fmaxf(a[r], 0.0f);
  }
  __syncthreads();
  if (t < 64){
    float a[8];
    #pragma unroll
    for (int r = 0; r < 8; r++) a[r] = ab2[t];
    const float4* wr = (const float4*)(aw2 + (size_t)t * 64);
    for (int j = 0; j < 16; j++){
      float4 w = wr[j];
      #pragma unroll
      for (int r = 0; r < 8; r++) a[r] += dot4(w, ((const float4*)ab[r])[j]);
    }
    #pragma unroll
    for (int r = 0; r < 8; r++) a2b[r][t] = fmaxf(a[r], 0.0f);
  }
  __syncthreads();
  if (t < 8){
    float p = ab3[0];
    for (int j = 0; j < 64; j++) p += aw3[j] * a2b[t][j];
    isinit[b0 + t] = (p > 0.0f) ? 1 : 0;   // sigmoid(p) > 0.5  <=>  p > 0
  }
}

// ---------------- K-nearest groups: one block per batch ----------------
__global__ __launch_bounds__(256) void k_groups(
    const float* __restrict__ thoughts, int* __restrict__ idxout)
{
  const int b = blockIdx.x;
  const int tid = threadIdx.x;
  __shared__ float T[64 * 130];
  __shared__ float sq[64];
  for (int p = tid; p < 8192; p += 256){
    T[(p >> 7) * 130 + (p & 127)] = thoughts[(size_t)b * 8192 + p];
  }
  __syncthreads();
  if (tid < 64){
    const float2* tj = (const float2*)&T[tid * 130];
    float s = 0.0f;
    #pragma unroll 8
    for (int k = 0; k < 64; k++){ float2 v = tj[k]; s += v.x*v.x + v.y*v.y; }
    sq[tid] = s;
  }
  __syncthreads();
  const int lane = tid & 63;
  const int wv = tid >> 6;
  const float2* tj = (const float2*)&T[lane * 130];
  const float sqj = sq[lane];
  for (int ii = 0; ii < 16; ii++){
    const int i = wv * 16 + ii;
    const float2* ti = (const float2*)&T[i * 130];
    float dot = 0.0f;
    #pragma unroll 8
    for (int k = 0; k < 64; k++){ float2 a = ti[k]; float2 c = tj[k]; dot += a.x*c.x + a.y*c.y; }
    float d = fmaxf(sq[i] + sqj - 2.0f*dot, 0.0f);   // clamp keeps uint-compare == float-compare
    u64 key = (((u64)__float_as_uint(d)) << 32) | (u32)lane;
    u64 mask = 0;
    for (int q = 0; q < 8; q++){
      u64 m = key;
      #pragma unroll
      for (int off = 32; off > 0; off >>= 1){ u64 o = __shfl_xor(m, off); if (o < m) m = o; }
      mask |= 1ull << (u32)(m & 63u);
      if (key == m) key = ~0ull;
    }
    if (lane == 0){
      u64 mm = mask;
      int base = (b * 64 + i) * 8;
      #pragma unroll
      for (int q = 0; q < 8; q++){ int j = (int)__builtin_ctzll(mm); mm &= mm - 1; idxout[base + q] = j; }
    }
  }
}

// ---------------- sequential gather -> bi-LSTM -> scatter: one block per batch ----------------
// 512 threads: tid = dir(1b) | h-row l(6b) | K-quarter q(2b).
// Each thread: quarter-dots for ALL 4 gates of h-row l (wi[4][16] h2 + wh[4][8] h2 in regs,
// ~115 VGPR demand < the measured 128 budget of a 512-thr block). The 4 quarters are adjacent
// lanes of the SAME wave -> combine with 2x __shfl_xor, then compute gates thread-locally:
// no zb round-trip, ONE barrier per step (was 2), all waves busy (was 2 of 8 at gate phase).
// Gates use v_exp_f32/v_rcp_f32 instead of libm expf/tanhf (~10 insts vs ~200).
// Packed h2 operands feed v_dot2_f32_f16 directly -> nothing for LLVM to hoist (r3 lesson).
__global__ __launch_bounds__(512) void k_scan(
    const float* __restrict__ thoughts, const int* __restrict__ isinit, const int* __restrict__ idx,
    const float* __restrict__ wihf, const float* __restrict__ whhf,
    const float* __restrict__ bihf, const float* __restrict__ bhhf,
    const float* __restrict__ wihb, const float* __restrict__ whhb,
    const float* __restrict__ bihb, const float* __restrict__ bhhb,
    float* __restrict__ newt)
{
  const int b   = blockIdx.x;
  const int tid = threadIdx.x;
  const int dir = tid >> 8;          // 0 fwd, 1 bwd
  const int l   = (tid >> 2) & 63;   // h index
  const int q   = tid & 3;           // K quarter

  __shared__ float nt[64 * 128];                   // 32 KB state
  __shared__ __align__(16) _Float16 X16[8 * 128];  // gathered X snapshot (f16)
  __shared__ __align__(16) _Float16 hb16[2][64];   // h state (f16)
  __shared__ int gall[512];
  __shared__ int flags[64];

  const float* wih = dir ? wihb : wihf;
  const float* whh = dir ? whhb : whhf;
  const float* bih = dir ? bihb : bihf;
  const float* bhh = dir ? bhhb : bhhf;

  h2 wi[4][16];   // wih[g*64+l, q*32 .. q*32+32)
  #pragma unroll
  for (int g = 0; g < 4; g++){
    const float2* wp = (const float2*)(wih + (size_t)(g * 64 + l) * 128 + q * 32);
    #pragma unroll
    for (int j = 0; j < 16; j++){ float2 w = wp[j]; wi[g][j] = pack_h2(w.x, w.y); }
  }
  h2 wh[4][8];    // whh[g*64+l, q*16 .. q*16+16)
  #pragma unroll
  for (int g = 0; g < 4; g++){
    const float2* wp = (const float2*)(whh + (size_t)(g * 64 + l) * 64 + q * 16);
    #pragma unroll
    for (int j = 0; j < 8; j++){ float2 w = wp[j]; wh[g][j] = pack_h2(w.x, w.y); }
  }
  float bs[4];    // bias counted once (q==0 lane only; shuffle-sum spreads it)
  #pragma unroll
  for (int g = 0; g < 4; g++) bs[g] = (q == 0) ? (bih[g * 64 + l] + bhh[g * 64 + l]) : 0.0f;

  for (int p = tid; p < 8192; p += 512) nt[p] = thoughts[(size_t)b * 8192 + p];
  gall[tid] = idx[(size_t)b * 512 + tid];
  if (tid < 64) flags[tid] = isinit[b * 64 + tid];
  __syncthreads();

  #pragma unroll 1
  for (int i = 0; i < 64; i++){
    if (!flags[i]) continue;            // uniform across block
    const int* gi = &gall[i * 8];
    { const int t = tid >> 6, cc = tid & 63;      // snapshot X -> f16 (1 h2/thread)
      float a  = nt[gi[t] * 128 + 2 * cc];
      float bv = nt[gi[t] * 128 + 2 * cc + 1];
      ((h2*)X16)[tid] = pack_h2(a, bv); }
    __syncthreads();

    float c = 0.0f;
    #pragma unroll 1
    for (int s = 0; s < 8; s++){
      const int tt = dir ? (7 - s) : s;
      float z0 = bs[0], z1 = bs[1], z2 = bs[2], z3 = bs[3];
      { const uint4* Xq = (const uint4*)&X16[tt * 128 + q * 32];
        #pragma unroll
        for (int j = 0; j < 4; j++){
          uint4 x = Xq[j];
          z0 = __builtin_amdgcn_fdot2(wi[0][4*j+0], u32_h2(x.x), z0, false);
          z0 = __builtin_amdgcn_fdot2(wi[0][4*j+1], u32_h2(x.y), z0, false);
          z0 = __builtin_amdgcn_fdot2(wi[0][4*j+2], u32_h2(x.z), z0, false);
          z0 = __builtin_amdgcn_fdot2(wi[0][4*j+3], u32_h2(x.w), z0, false);
          z1 = __builtin_amdgcn_fdot2(wi[1][4*j+0], u32_h2(x.x), z1, false);
          z1 = __builtin_amdgcn_fdot2(wi[1][4*j+1], u32_h2(x.y), z1, false);
          z1 = __builtin_amdgcn_fdot2(wi[1][4*j+2], u32_h2(x.z), z1, false);
          z1 = __builtin_amdgcn_fdot2(wi[1][4*j+3], u32_h2(x.w), z1, false);
          z2 = __builtin_amdgcn_fdot2(wi[2][4*j+0], u32_h2(x.x), z2, false);
          z2 = __builtin_amdgcn_fdot2(wi[2][4*j+1], u32_h2(x.y), z2, false);
          z2 = __builtin_amdgcn_fdot2(wi[2][4*j+2], u32_h2(x.z), z2, false);
          z2 = __builtin_amdgcn_fdot2(wi[2][4*j+3], u32_h2(x.w), z2, false);
          z3 = __builtin_amdgcn_fdot2(wi[3][4*j+0], u32_h2(x.x), z3, false);
          z3 = __builtin_amdgcn_fdot2(wi[3][4*j+1], u32_h2(x.y), z3, false);
          z3 = __builtin_amdgcn_fdot2(wi[3][4*j+2], u32_h2(x.z), z3, false);
          z3 = __builtin_amdgcn_fdot2(wi[3][4*j+3], u32_h2(x.w), z3, false);
        } }
      if (s > 0){
        const uint4* Hq = (const uint4*)&hb16[dir][q * 16];
        #pragma unroll
        for (int j = 0; j < 2; j++){
          uint4 h = Hq[j];
          z0 = __builtin_amdgcn_fdot2(wh[0][4*j+0], u32_h2(h.x), z0, false);
          z0 = __builtin_amdgcn_fdot2(wh[0][4*j+1], u32_h2(h.y), z0, false);
          z0 = __builtin_amdgcn_fdot2(wh[0][4*j+2], u32_h2(h.z), z0, false);
          z0 = __builtin_amdgcn_fdot2(wh[0][4*j+3], u32_h2(h.w), z0, false);
          z1 = __builtin_amdgcn_fdot2(wh[1][4*j+0], u32_h2(h.x), z1, false);
          z1 = __builtin_amdgcn_fdot2(wh[1][4*j+1], u32_h2(h.y), z1, false);
          z1 = __builtin_amdgcn_fdot2(wh[1][4*j+2], u32_h2(h.z), z1, false);
          z1 = __builtin_amdgcn_fdot2(wh[1][4*j+3], u32_h2(h.w), z1, false);
          z2 = __builtin_amdgcn_fdot2(wh[2][4*j+0], u32_h2(h.x), z2, false);
          z2 = __builtin_amdgcn_fdot2(wh[2][4*j+1], u32_h2(h.y), z2, false);
          z2 = __builtin_amdgcn_fdot2(wh[2][4*j+2], u32_h2(h.z), z2, false);
          z2 = __builtin_amdgcn_fdot2(wh[2][4*j+3], u32_h2(h.w), z2, false);
          z3 = __builtin_amdgcn_fdot2(wh[3][4*j+0], u32_h2(h.x), z3, false);
          z3 = __builtin_amdgcn_fdot2(wh[3][4*j+1], u32_h2(h.y), z3, false);
          z3 = __builtin_amdgcn_fdot2(wh[3][4*j+2], u32_h2(h.z), z3, false);
          z3 = __builtin_amdgcn_fdot2(wh[3][4*j+3], u32_h2(h.w), z3, false);
        } }
      // combine the 4 K-quarters (adjacent lanes, same wave)
      z0 += __shfl_xor(z0, 1); z0 += __shfl_xor(z0, 2);
      z1 += __shfl_xor(z1, 1); z1 += __shfl_xor(z1, 2);
      z2 += __shfl_xor(z2, 1); z2 += __shfl_xor(z2, 2);
      z3 += __shfl_xor(z3, 1); z3 += __shfl_xor(z3, 2);
      // gates thread-local (i,f,g,o); c redundant-consistent across the 4 q-lanes
      float fi = fsig(z0);
      float ff = fsig(z1);
      float fg = ftanh(z2);
      float fo = fsig(z3);
      c = ff * c + fi * fg;
      float hn = fo * ftanh(c);
      if (q == 0){
        hb16[dir][l] = (_Float16)hn;
        nt[gi[tt] * 128 + dir * 64 + l] = hn;
      }
      __syncthreads();
    }
  }
  for (int p = tid; p < 8192; p += 512) newt[(size_t)b * 8192 + p] = nt[p];
}

// ---------------- actor_2: 8 rows per block, 128 threads ----------------
__global__ __launch_bounds__(128) void k_actor2(
    const float* __restrict__ thoughts, const float* __restrict__ newt,
    const float* __restrict__ w1, const float* __restrict__ b1, const float* __restrict__ w2,
    float* __restrict__ out)
{
  const int b0 = blockIdx.x * 8;
  const int t = threadIdx.x;
  __shared__ float xs[8][256];
  __shared__ float ybuf[8][128];
  for (int p = t; p < 2048; p += 128){
    int r = p >> 8, c = p & 255;
    float v = (c < 128) ? thoughts[(size_t)(b0 + r) * 128 + c]
                        : newt[(size_t)(b0 + r) * 128 + (c - 128)];
    xs[r][c] = fmaxf(v, 0.0f);
  }
  __syncthreads();
  float acc[8];
  #pragma unroll
  for (int r = 0; r < 8; r++) acc[r] = b1[t];
  { const float4* wr = (const float4*)(w1 + (size_t)t * 256);
    for (int j = 0; j < 64; j++){
      float4 w = wr[j];
      #pragma unroll
      for (int r = 0; r < 8; r++) acc[r] += dot4(w, ((const float4*)xs[r])[j]);
    } }
  #pragma unroll
  for (int r = 0; r < 8; r++) ybuf[r][t] = acc[r];
  __syncthreads();
  if (t < 64){
    float a[8];
    #pragma unroll
    for (int r = 0; r < 8; r++) a[r] = 0.0f;
    const float4* wr = (const float4*)(w2 + (size_t)t * 128);
    for (int j = 0; j < 32; j++){
      float4 w = wr[j];
      #pragma unroll
      for (int r = 0; r < 8; r++) a[r] += dot4(w, ((const float4*)ybuf[r])[j]);
    }
    #pragma unroll
    for (int r = 0; r < 8; r++) out[(size_t)(b0 + r) * 64 + t] = ftanh(a[r]);
  }
}

extern "C" void kernel_launch(void* const* d_in, const int* in_sizes, int n_in,
                              void* d_out, int out_size, void* d_ws, size_t ws_size,
                              hipStream_t stream)
{
  const float* obs  = (const float*)d_in[0];
  const float* w1   = (const float*)d_in[1];
  const float* b1   = (const float*)d_in[2];
  const float* lng  = (const float*)d_in[3];
  const float* lnb  = (const float*)d_in[4];
  const float* w2   = (const float*)d_in[5];
  const float* b2   = (const float*)d_in[6];
  const float* aw1  = (const float*)d_in[7];
  const float* ab1  = (const float*)d_in[8];
  const float* aw2  = (const float*)d_in[9];
  const float* ab2  = (const float*)d_in[10];
  const float* aw3  = (const float*)d_in[11];
  const float* ab3  = (const float*)d_in[12];
  const float* wihf = (const float*)d_in[13];
  const float* whhf = (const float*)d_in[14];
  const float* bihf = (const float*)d_in[15];
  const float* bhhf = (const float*)d_in[16];
  const float* wihb = (const float*)d_in[17];
  const float* whhb = (const float*)d_in[18];
  const float* bihb = (const float*)d_in[19];
  const float* bhhb = (const float*)d_in[20];
  const float* a2w1 = (const float*)d_in[21];
  const float* a2b1 = (const float*)d_in[22];
  const float* a2w2 = (const float*)d_in[23];

  float* thoughts = (float*)d_ws;                       // 33.5 MB
  float* newt     = thoughts + (size_t)ROWS * 128;      // 33.5 MB
  int*   isinit   = (int*)(newt + (size_t)ROWS * 128);  // 256 KB
  int*   idxb     = isinit + ROWS;                      // 2 MB

  hipLaunchKernelGGL(k_actor1, dim3(ROWS / 8), dim3(128), 0, stream,
                     obs, w1, b1, lng, lnb, w2, b2, aw1, ab1, aw2, ab2, aw3, ab3,
                     thoughts, isinit);
  hipLaunchKernelGGL(k_groups, dim3(NB), dim3(256), 0, stream, thoughts, idxb);
  hipLaunchKernelGGL(k_scan, dim3(NB), dim3(512), 0, stream,
                     thoughts, isinit, idxb,
                     wihf, whhf, bihf, bhhf, wihb, whhb, bihb, bhhb, newt);
  hipLaunchKernelGGL(k_actor2, dim3(ROWS / 8), dim3(128), 0, stream,
                     thoughts, newt, a2w1, a2b1, a2w2, (float*)d_out);
}